// Round 6
// baseline (493.462 us; speedup 1.0000x reference)
//
#include <hip/hip_runtime.h>
#include <hip/hip_bf16.h>

#define HIDDEN 512
#define IMGF   2048
#define RNDS   10
#define NBLK   640

typedef float  f32x4  __attribute__((ext_vector_type(4)));
typedef __bf16 bf16x8 __attribute__((ext_vector_type(8)));
typedef unsigned short u16x8 __attribute__((ext_vector_type(8)));

__device__ __forceinline__ unsigned short f2bf(float x) {
    union { float f; unsigned u; } v; v.f = x;
    unsigned r = v.u + 0x7FFFu + ((v.u >> 16) & 1u);   // RNE
    return (unsigned short)(r >> 16);
}
__device__ __forceinline__ float bf2f(unsigned short h) {
    union { unsigned u; float f; } v; v.u = ((unsigned)h) << 16;
    return v.f;
}

__device__ __forceinline__ void cp16_async(const void* g, void* l) {
    __builtin_amdgcn_global_load_lds(
        (const __attribute__((address_space(1))) unsigned int*)g,
        (__attribute__((address_space(3))) unsigned int*)l,
        16, 0, 0);
}

// --- grid barrier, cg-style: one RELEASE fetch_add arrive per block, then a
// LOAD-ONLY acquire spin with s_sleep backoff. Round 5's atomicAdd(p,0) RMW
// spin serialized 640 blocks at the coherent point (~190us across 3 barriers:
// MfmaUtil 2%/VALUBusy 5%/HBM 6% all idle). Loads don't serialize; REL/ACQ
// scoped atomics emit the needed L2 writeback/invalidate (no __threadfence).
// Deadlock-free by construction: launch_bounds(256,3) -> VGPR<=170 -> 3 blk/CU
// x 256 CU = 768 resident slots >= 640 blocks.
#define GRID_BARRIER(CNT)                                                       \
    __syncthreads();                                                            \
    if (t == 0) {                                                               \
        __hip_atomic_fetch_add((CNT), 1u, __ATOMIC_RELEASE,                     \
                               __HIP_MEMORY_SCOPE_AGENT);                       \
        while (__hip_atomic_load((CNT), __ATOMIC_ACQUIRE,                       \
                                 __HIP_MEMORY_SCOPE_AGENT) < NBLK)              \
            __builtin_amdgcn_s_sleep(16);                                       \
    }                                                                           \
    __syncthreads();

// --- one K-step of async staging: A(64x64) + B(64x64), 512 16B chunks each,
// chunk-col XOR-swizzled by (row&7). Uses g_A0/g_lda0/g_A1/g_lda1/g_ks/g_K/
// g_Wb/bm bound in the enclosing block.
#define STAGE_TILES(KT, BUF) {                                          \
    int k0_ = (KT) << 6;                                                \
    const unsigned short* Ab_; int lda_;                                \
    if (k0_ < g_ks) { Ab_ = g_A0 + (size_t)bm * g_lda0 + k0_;            lda_ = g_lda0; } \
    else            { Ab_ = g_A1 + (size_t)bm * g_lda1 + (k0_ - g_ks);   lda_ = g_lda1; } \
    for (int h_ = 0; h_ < 2; ++h_) {                                    \
        int ci_ = h_ * 256 + t;                                         \
        int r_ = ci_ >> 3, s_ = (ci_ & 7) ^ (r_ & 7);                   \
        cp16_async(Ab_ + (size_t)r_ * lda_ + s_ * 8, &lA[BUF][ci_ * 8]); \
        cp16_async(g_Wb + k0_ + (size_t)r_ * g_K + s_ * 8, &lB[BUF][ci_ * 8]); \
    } }

// --- double-buffered K-loop + 2x2 16x16x32 MFMA per wave per k-half.
#define GEMM_KLOOP(NT)                                                  \
    STAGE_TILES(0, 0);                                                  \
    for (int kt = 0; kt < (NT); ++kt) {                                 \
        __syncthreads();                                                \
        if (kt + 1 < (NT)) STAGE_TILES(kt + 1, (kt + 1) & 1);           \
        const unsigned short* a_ = &lA[kt & 1][0];                      \
        const unsigned short* b_ = &lB[kt & 1][0];                      \
        for (int kh = 0; kh < 2; ++kh) {                                \
            const int c_ = kh * 4 + lq;                                 \
            const int ra0 = wm + lr,      ra1 = wm + 16 + lr;           \
            const int rb0 = wn + lr,      rb1 = wn + 16 + lr;           \
            bf16x8 af0 = __builtin_bit_cast(bf16x8, *(const u16x8*)&a_[ra0 * 64 + ((c_ ^ (ra0 & 7)) * 8)]); \
            bf16x8 af1 = __builtin_bit_cast(bf16x8, *(const u16x8*)&a_[ra1 * 64 + ((c_ ^ (ra1 & 7)) * 8)]); \
            bf16x8 bf0 = __builtin_bit_cast(bf16x8, *(const u16x8*)&b_[rb0 * 64 + ((c_ ^ (rb0 & 7)) * 8)]); \
            bf16x8 bf1 = __builtin_bit_cast(bf16x8, *(const u16x8*)&b_[rb1 * 64 + ((c_ ^ (rb1 & 7)) * 8)]); \
            acc00 = __builtin_amdgcn_mfma_f32_16x16x32_bf16(af0, bf0, acc00, 0, 0, 0); \
            acc01 = __builtin_amdgcn_mfma_f32_16x16x32_bf16(af0, bf1, acc01, 0, 0, 0); \
            acc10 = __builtin_amdgcn_mfma_f32_16x16x32_bf16(af1, bf0, acc10, 0, 0, 0); \
            acc11 = __builtin_amdgcn_mfma_f32_16x16x32_bf16(af1, bf1, acc11, 0, 0, 0); \
        }                                                               \
    }                                                                   \
    __syncthreads();

// --- epilogue fragments: D[m = lq*4+j][n = lr]  (verified m89/m91 layout)
#define EPI_BF16(ACC, MI, NI, BIAS, DST) {                              \
    const int col_ = bn + wn + (NI) * 16 + lr;                          \
    const float bc_ = (BIAS)[col_];                                     \
    const int rb_ = bm + wm + (MI) * 16 + lq * 4;                       \
    for (int j_ = 0; j_ < 4; ++j_) {                                    \
        const size_t idx_ = (size_t)(rb_ + j_) * HIDDEN + col_;         \
        (DST)[idx_] = f2bf(tanhf(ACC[j_] + bc_));                       \
    } }

#define EPI_RESID(ACC, MI, NI, BIAS, RESB, DST) {                       \
    const int col_ = bn + wn + (NI) * 16 + lr;                          \
    const float bc_ = (BIAS)[col_];                                     \
    const int rb_ = bm + wm + (MI) * 16 + lq * 4;                       \
    for (int j_ = 0; j_ < 4; ++j_) {                                    \
        const size_t idx_ = (size_t)(rb_ + j_) * HIDDEN + col_;         \
        (DST)[idx_] = tanhf(ACC[j_] + bc_) + bf2f((RESB)[idx_]);        \
    } }

// ===========================================================================
// Single mega-kernel: cvt -> gemm1 -> attn -> gemm2 with manual grid
// barriers. 640 blocks x 256 thr, 32 KB LDS. No lambdas / device fns
// touching LDS (clang-22 segfaults); repeated code is textual macros.
// Math byte-identical to the verified round-0/1 4-kernel pipeline.
// ===========================================================================
__global__ __launch_bounds__(256, 3)
void mega(const float* __restrict__ img,   const float* __restrict__ ques,
          const float* __restrict__ hist,
          const float* __restrict__ b_fuse, const float* __restrict__ w_att,
          const float* __restrict__ b_att,  const float* __restrict__ b_hist,
          const float* __restrict__ W_fuse, const float* __restrict__ W_hist,
          unsigned short* __restrict__ imgb,   unsigned short* __restrict__ quesb,
          unsigned short* __restrict__ Wfb,    unsigned short* __restrict__ Whb,
          unsigned short* __restrict__ fusedb, unsigned short* __restrict__ hembb,
          float* __restrict__ out, unsigned* __restrict__ bar,
          long n_img, long n_ques, long n_Wf, long n_Wh, int BR)
{
    __shared__ unsigned short lA[2][64 * 64];
    __shared__ unsigned short lB[2][64 * 64];

    const int t    = threadIdx.x;
    const int lane = t & 63;
    const int wave = t >> 6;
    const int bx   = blockIdx.x;

    // ---- phase 0: fp32 -> bf16 (img, ques, W_fuse, W_hist), grid-stride ----
    {
        const long total  = n_img + n_ques + n_Wf + n_Wh;
        const long stride = (long)NBLK * 256 * 4;
        for (long i = ((long)bx * 256 + t) * 4; i < total; i += stride) {
            const float* sp; unsigned short* dp; long j;
            if      (i < n_img)                  { sp = img;    dp = imgb;  j = i; }
            else if (i < n_img + n_ques)         { sp = ques;   dp = quesb; j = i - n_img; }
            else if (i < n_img + n_ques + n_Wf)  { sp = W_fuse; dp = Wfb;   j = i - n_img - n_ques; }
            else                                 { sp = W_hist; dp = Whb;   j = i - n_img - n_ques - n_Wf; }
            float4 v = *(const float4*)(sp + j);
            ushort4 o;
            o.x = f2bf(v.x); o.y = f2bf(v.y); o.z = f2bf(v.z); o.w = f2bf(v.w);
            *(ushort4*)(dp + j) = o;
        }
    }
    GRID_BARRIER(bar + 0)

    // block -> (bm, bn): XCD-contiguous bm ranges (A panels stay in one L2)
    const int xcd = bx & 7, bj = bx >> 3;
    const int bm  = (xcd * 10 + (bj % 10)) * 64;   // 80 row tiles
    const int bn  = (bj / 10) * 64;                // 8 col tiles

    const int wm = (wave >> 1) * 32;   // 0 / 32
    const int wn = (wave & 1) * 32;    // 0 / 32
    const int lr = lane & 15;
    const int lq = lane >> 4;

    // ---- phase 1: fused = tanh(cat(img,ques) @ W_fuse^T + b_fuse) ----
    {
        const unsigned short* g_A0 = imgb;  const int g_lda0 = IMGF;
        const unsigned short* g_A1 = quesb; const int g_lda1 = HIDDEN;
        const int g_ks = IMGF;
        const int g_K  = IMGF + HIDDEN;
        const unsigned short* g_Wb = Wfb + (size_t)bn * g_K;
        f32x4 acc00 = {}, acc01 = {}, acc10 = {}, acc11 = {};
        GEMM_KLOOP(40)
        EPI_BF16(acc00, 0, 0, b_fuse, fusedb)
        EPI_BF16(acc01, 0, 1, b_fuse, fusedb)
        EPI_BF16(acc10, 1, 0, b_fuse, fusedb)
        EPI_BF16(acc11, 1, 1, b_fuse, fusedb)
    }
    GRID_BARRIER(bar + 64)

    // ---- phase 2: attention + weighted history sum (2 rows per wave) ----
    {
        const float ba = b_att[0];
        const int gw = bx * 4 + wave;
        for (int rr = 0; rr < 2; ++rr) {
            const int b = gw * 2 + rr;
            if (b < BR) {
                const int d = lane * 8;
                float g[8];
                {
                    u16x8 f = *(const u16x8*)(fusedb + (size_t)b * HIDDEN + d);
                    const float4 w0 = *(const float4*)(w_att + d);
                    const float4 w1 = *(const float4*)(w_att + d + 4);
                    g[0]=bf2f(f[0])*w0.x; g[1]=bf2f(f[1])*w0.y;
                    g[2]=bf2f(f[2])*w0.z; g[3]=bf2f(f[3])*w0.w;
                    g[4]=bf2f(f[4])*w1.x; g[5]=bf2f(f[5])*w1.y;
                    g[6]=bf2f(f[6])*w1.z; g[7]=bf2f(f[7])*w1.w;
                }
                const float* hb = hist + (size_t)b * RNDS * HIDDEN + d;

                float h[RNDS][8], p[RNDS];
                for (int r = 0; r < RNDS; ++r) {
                    const float4 a0 = *(const float4*)(hb + r * HIDDEN);
                    const float4 a1 = *(const float4*)(hb + r * HIDDEN + 4);
                    h[r][0]=a0.x; h[r][1]=a0.y; h[r][2]=a0.z; h[r][3]=a0.w;
                    h[r][4]=a1.x; h[r][5]=a1.y; h[r][6]=a1.z; h[r][7]=a1.w;
                    float s = 0.f;
                    for (int i = 0; i < 8; ++i) s += h[r][i] * g[i];
                    p[r] = s;
                }
                for (int r = 0; r < RNDS; ++r)
                    for (int m = 1; m < 64; m <<= 1)
                        p[r] += __shfl_xor(p[r], m, 64);

                float mx = -1e30f;
                for (int r = 0; r < RNDS; ++r) mx = fmaxf(mx, p[r] + ba);
                float sum = 0.f, a[RNDS];
                for (int r = 0; r < RNDS; ++r) { a[r] = __expf(p[r] + ba - mx); sum += a[r]; }
                const float inv = 1.0f / sum;

                float e[8] = {};
                for (int r = 0; r < RNDS; ++r)
                    for (int i = 0; i < 8; ++i) e[i] += a[r] * h[r][i];

                ushort4 o0, o1;
                o0.x=f2bf(e[0]*inv); o0.y=f2bf(e[1]*inv);
                o0.z=f2bf(e[2]*inv); o0.w=f2bf(e[3]*inv);
                o1.x=f2bf(e[4]*inv); o1.y=f2bf(e[5]*inv);
                o1.z=f2bf(e[6]*inv); o1.w=f2bf(e[7]*inv);
                unsigned short* q = hembb + (size_t)b * HIDDEN + d;
                *(ushort4*)q = o0;
                *(ushort4*)(q + 4) = o1;
            }
        }
    }
    GRID_BARRIER(bar + 128)

    // ---- phase 3: out = fused + tanh(hembb @ W_hist^T + b_hist) ----
    {
        const unsigned short* g_A0 = hembb; const int g_lda0 = HIDDEN;
        const unsigned short* g_A1 = hembb; const int g_lda1 = HIDDEN;
        const int g_ks = HIDDEN;           // k0 < 512 always -> A0 branch
        const int g_K  = HIDDEN;
        const unsigned short* g_Wb = Whb + (size_t)bn * g_K;
        f32x4 acc00 = {}, acc01 = {}, acc10 = {}, acc11 = {};
        GEMM_KLOOP(8)
        EPI_RESID(acc00, 0, 0, b_hist, fusedb, out)
        EPI_RESID(acc01, 0, 1, b_hist, fusedb, out)
        EPI_RESID(acc10, 1, 0, b_hist, fusedb, out)
        EPI_RESID(acc11, 1, 1, b_hist, fusedb, out)
    }
}

extern "C" void kernel_launch(void* const* d_in, const int* in_sizes, int n_in,
                              void* d_out, int out_size, void* d_ws, size_t ws_size,
                              hipStream_t stream)
{
    const float* img    = (const float*)d_in[0];
    const float* ques   = (const float*)d_in[1];
    const float* hist   = (const float*)d_in[2];
    const float* W_fuse = (const float*)d_in[3];
    const float* b_fuse = (const float*)d_in[4];
    const float* w_att  = (const float*)d_in[5];
    const float* b_att  = (const float*)d_in[6];
    const float* W_hist = (const float*)d_in[7];
    const float* b_hist = (const float*)d_in[8];

    long n_img  = in_sizes[0];
    long n_ques = in_sizes[1];
    long n_Wf   = in_sizes[3];
    long n_Wh   = in_sizes[7];
    int  BR     = (int)(n_ques / HIDDEN);   // 5120

    unsigned short* imgb   = (unsigned short*)d_ws;
    unsigned short* quesb  = imgb   + n_img;
    unsigned short* Wfb    = quesb  + n_ques;
    unsigned short* Whb    = Wfb    + n_Wf;
    unsigned short* fusedb = Whb    + n_Wh;        // BR*512 bf16
    unsigned short* hembb  = fusedb + (size_t)BR * HIDDEN;
    size_t bar_off = (size_t)((char*)(hembb + (size_t)BR * HIDDEN) - (char*)d_ws);
    bar_off = (bar_off + 255) & ~(size_t)255;
    unsigned* bar = (unsigned*)((char*)d_ws + bar_off);
    float* outp = (float*)d_out;

    // zero the 3 barrier counters (word offsets 0 / 64 / 128 -> 256B apart,
    // so spin traffic on one counter's line never aliases another's)
    hipMemsetAsync(bar, 0, 192 * sizeof(unsigned), stream);

    mega<<<dim3(NBLK), dim3(256), 0, stream>>>(
        img, ques, hist, b_fuse, w_att, b_att, b_hist, W_fuse, W_hist,
        imgb, quesb, Wfb, Whb, fusedb, hembb, outp, bar,
        n_img, n_ques, n_Wf, n_Wh, BR);
}

// Round 7
// 412.101 us; speedup vs baseline: 1.1974x; 1.1974x over previous
//
#include <hip/hip_runtime.h>
#include <hip/hip_bf16.h>

#define HIDDEN 512
#define IMGF   2048
#define RNDS   10
#define NBLK   640

typedef float  f32x4  __attribute__((ext_vector_type(4)));
typedef __bf16 bf16x8 __attribute__((ext_vector_type(8)));
typedef unsigned short u16x8 __attribute__((ext_vector_type(8)));

__device__ __forceinline__ unsigned short f2bf(float x) {
    union { float f; unsigned u; } v; v.f = x;
    unsigned r = v.u + 0x7FFFu + ((v.u >> 16) & 1u);   // RNE
    return (unsigned short)(r >> 16);
}
__device__ __forceinline__ float bf2f(unsigned short h) {
    union { unsigned u; float f; } v; v.u = ((unsigned)h) << 16;
    return v.f;
}

__device__ __forceinline__ void cp16_async(const void* g, void* l) {
    __builtin_amdgcn_global_load_lds(
        (const __attribute__((address_space(1))) unsigned int*)g,
        (__attribute__((address_space(3))) unsigned int*)l,
        16, 0, 0);
}

// --- grid barrier, v3. Rounds 5/6 spun with agent-scope ACQUIRE ops; on
// gfx950 every acquire poll emits buffer_inv sc1 (XCD L2 invalidate), so
// early-arriving blocks continuously trashed the L2 of blocks still working
// (both variants ~equal, all pipes idle -> mechanism was cache-op per poll,
// not RMW serialization). v3: RELAXED poll (no cache op, coherent-point
// read), then ONE acquire fence after exit (single buffer_inv per block per
// barrier). Arrive = one RELEASE fetch_add (single L2 writeback, publishes
// this block's outputs). Deadlock-free: launch_bounds(256,3) -> 3 blk/CU
// x 256 CU = 768 resident slots >= 640 blocks, all co-resident.
#define GRID_BARRIER(CNT)                                                       \
    __syncthreads();                                                            \
    if (t == 0) {                                                               \
        __hip_atomic_fetch_add((CNT), 1u, __ATOMIC_RELEASE,                     \
                               __HIP_MEMORY_SCOPE_AGENT);                       \
        while (__hip_atomic_load((CNT), __ATOMIC_RELAXED,                       \
                                 __HIP_MEMORY_SCOPE_AGENT) < NBLK)              \
            __builtin_amdgcn_s_sleep(8);                                        \
        __builtin_amdgcn_fence(__ATOMIC_ACQUIRE, "agent");                      \
    }                                                                           \
    __syncthreads();

// --- one K-step of async staging: A(64x64) + B(64x64), 512 16B chunks each,
// chunk-col XOR-swizzled by (row&7). Uses g_A0/g_lda0/g_A1/g_lda1/g_ks/g_K/
// g_Wb/bm bound in the enclosing block.
#define STAGE_TILES(KT, BUF) {                                          \
    int k0_ = (KT) << 6;                                                \
    const unsigned short* Ab_; int lda_;                                \
    if (k0_ < g_ks) { Ab_ = g_A0 + (size_t)bm * g_lda0 + k0_;            lda_ = g_lda0; } \
    else            { Ab_ = g_A1 + (size_t)bm * g_lda1 + (k0_ - g_ks);   lda_ = g_lda1; } \
    for (int h_ = 0; h_ < 2; ++h_) {                                    \
        int ci_ = h_ * 256 + t;                                         \
        int r_ = ci_ >> 3, s_ = (ci_ & 7) ^ (r_ & 7);                   \
        cp16_async(Ab_ + (size_t)r_ * lda_ + s_ * 8, &lA[BUF][ci_ * 8]); \
        cp16_async(g_Wb + k0_ + (size_t)r_ * g_K + s_ * 8, &lB[BUF][ci_ * 8]); \
    } }

// --- double-buffered K-loop + 2x2 16x16x32 MFMA per wave per k-half.
#define GEMM_KLOOP(NT)                                                  \
    STAGE_TILES(0, 0);                                                  \
    for (int kt = 0; kt < (NT); ++kt) {                                 \
        __syncthreads();                                                \
        if (kt + 1 < (NT)) STAGE_TILES(kt + 1, (kt + 1) & 1);           \
        const unsigned short* a_ = &lA[kt & 1][0];                      \
        const unsigned short* b_ = &lB[kt & 1][0];                      \
        for (int kh = 0; kh < 2; ++kh) {                                \
            const int c_ = kh * 4 + lq;                                 \
            const int ra0 = wm + lr,      ra1 = wm + 16 + lr;           \
            const int rb0 = wn + lr,      rb1 = wn + 16 + lr;           \
            bf16x8 af0 = __builtin_bit_cast(bf16x8, *(const u16x8*)&a_[ra0 * 64 + ((c_ ^ (ra0 & 7)) * 8)]); \
            bf16x8 af1 = __builtin_bit_cast(bf16x8, *(const u16x8*)&a_[ra1 * 64 + ((c_ ^ (ra1 & 7)) * 8)]); \
            bf16x8 bf0 = __builtin_bit_cast(bf16x8, *(const u16x8*)&b_[rb0 * 64 + ((c_ ^ (rb0 & 7)) * 8)]); \
            bf16x8 bf1 = __builtin_bit_cast(bf16x8, *(const u16x8*)&b_[rb1 * 64 + ((c_ ^ (rb1 & 7)) * 8)]); \
            acc00 = __builtin_amdgcn_mfma_f32_16x16x32_bf16(af0, bf0, acc00, 0, 0, 0); \
            acc01 = __builtin_amdgcn_mfma_f32_16x16x32_bf16(af0, bf1, acc01, 0, 0, 0); \
            acc10 = __builtin_amdgcn_mfma_f32_16x16x32_bf16(af1, bf0, acc10, 0, 0, 0); \
            acc11 = __builtin_amdgcn_mfma_f32_16x16x32_bf16(af1, bf1, acc11, 0, 0, 0); \
        }                                                               \
    }                                                                   \
    __syncthreads();

// --- epilogue fragments: D[m = lq*4+j][n = lr]  (verified m89/m91 layout)
#define EPI_BF16(ACC, MI, NI, BIAS, DST) {                              \
    const int col_ = bn + wn + (NI) * 16 + lr;                          \
    const float bc_ = (BIAS)[col_];                                     \
    const int rb_ = bm + wm + (MI) * 16 + lq * 4;                       \
    for (int j_ = 0; j_ < 4; ++j_) {                                    \
        const size_t idx_ = (size_t)(rb_ + j_) * HIDDEN + col_;         \
        (DST)[idx_] = f2bf(tanhf(ACC[j_] + bc_));                       \
    } }

#define EPI_RESID(ACC, MI, NI, BIAS, RESB, DST) {                       \
    const int col_ = bn + wn + (NI) * 16 + lr;                          \
    const float bc_ = (BIAS)[col_];                                     \
    const int rb_ = bm + wm + (MI) * 16 + lq * 4;                       \
    for (int j_ = 0; j_ < 4; ++j_) {                                    \
        const size_t idx_ = (size_t)(rb_ + j_) * HIDDEN + col_;         \
        (DST)[idx_] = tanhf(ACC[j_] + bc_) + bf2f((RESB)[idx_]);        \
    } }

// ===========================================================================
// Single mega-kernel: cvt -> gemm1 -> attn -> gemm2 with manual grid
// barriers. 640 blocks x 256 thr, 32 KB LDS. No lambdas / device fns
// touching LDS (clang-22 segfaults); repeated code is textual macros.
// Math byte-identical to the verified round-0/1 4-kernel pipeline.
// ===========================================================================
__global__ __launch_bounds__(256, 3)
void mega(const float* __restrict__ img,   const float* __restrict__ ques,
          const float* __restrict__ hist,
          const float* __restrict__ b_fuse, const float* __restrict__ w_att,
          const float* __restrict__ b_att,  const float* __restrict__ b_hist,
          const float* __restrict__ W_fuse, const float* __restrict__ W_hist,
          unsigned short* __restrict__ imgb,   unsigned short* __restrict__ quesb,
          unsigned short* __restrict__ Wfb,    unsigned short* __restrict__ Whb,
          unsigned short* __restrict__ fusedb, unsigned short* __restrict__ hembb,
          float* __restrict__ out, unsigned* __restrict__ bar,
          long n_img, long n_ques, long n_Wf, long n_Wh, int BR)
{
    __shared__ unsigned short lA[2][64 * 64];
    __shared__ unsigned short lB[2][64 * 64];

    const int t    = threadIdx.x;
    const int lane = t & 63;
    const int wave = t >> 6;
    const int bx   = blockIdx.x;

    // ---- phase 0: fp32 -> bf16 (img, ques, W_fuse, W_hist), grid-stride ----
    {
        const long total  = n_img + n_ques + n_Wf + n_Wh;
        const long stride = (long)NBLK * 256 * 4;
        for (long i = ((long)bx * 256 + t) * 4; i < total; i += stride) {
            const float* sp; unsigned short* dp; long j;
            if      (i < n_img)                  { sp = img;    dp = imgb;  j = i; }
            else if (i < n_img + n_ques)         { sp = ques;   dp = quesb; j = i - n_img; }
            else if (i < n_img + n_ques + n_Wf)  { sp = W_fuse; dp = Wfb;   j = i - n_img - n_ques; }
            else                                 { sp = W_hist; dp = Whb;   j = i - n_img - n_ques - n_Wf; }
            float4 v = *(const float4*)(sp + j);
            ushort4 o;
            o.x = f2bf(v.x); o.y = f2bf(v.y); o.z = f2bf(v.z); o.w = f2bf(v.w);
            *(ushort4*)(dp + j) = o;
        }
    }
    GRID_BARRIER(bar + 0)

    // block -> (bm, bn): XCD-contiguous bm ranges (A panels stay in one L2)
    const int xcd = bx & 7, bj = bx >> 3;
    const int bm  = (xcd * 10 + (bj % 10)) * 64;   // 80 row tiles
    const int bn  = (bj / 10) * 64;                // 8 col tiles

    const int wm = (wave >> 1) * 32;   // 0 / 32
    const int wn = (wave & 1) * 32;    // 0 / 32
    const int lr = lane & 15;
    const int lq = lane >> 4;

    // ---- phase 1: fused = tanh(cat(img,ques) @ W_fuse^T + b_fuse) ----
    {
        const unsigned short* g_A0 = imgb;  const int g_lda0 = IMGF;
        const unsigned short* g_A1 = quesb; const int g_lda1 = HIDDEN;
        const int g_ks = IMGF;
        const int g_K  = IMGF + HIDDEN;
        const unsigned short* g_Wb = Wfb + (size_t)bn * g_K;
        f32x4 acc00 = {}, acc01 = {}, acc10 = {}, acc11 = {};
        GEMM_KLOOP(40)
        EPI_BF16(acc00, 0, 0, b_fuse, fusedb)
        EPI_BF16(acc01, 0, 1, b_fuse, fusedb)
        EPI_BF16(acc10, 1, 0, b_fuse, fusedb)
        EPI_BF16(acc11, 1, 1, b_fuse, fusedb)
    }
    GRID_BARRIER(bar + 64)

    // ---- phase 2: attention + weighted history sum (2 rows per wave) ----
    {
        const float ba = b_att[0];
        const int gw = bx * 4 + wave;
        for (int rr = 0; rr < 2; ++rr) {
            const int b = gw * 2 + rr;
            if (b < BR) {
                const int d = lane * 8;
                float g[8];
                {
                    u16x8 f = *(const u16x8*)(fusedb + (size_t)b * HIDDEN + d);
                    const float4 w0 = *(const float4*)(w_att + d);
                    const float4 w1 = *(const float4*)(w_att + d + 4);
                    g[0]=bf2f(f[0])*w0.x; g[1]=bf2f(f[1])*w0.y;
                    g[2]=bf2f(f[2])*w0.z; g[3]=bf2f(f[3])*w0.w;
                    g[4]=bf2f(f[4])*w1.x; g[5]=bf2f(f[5])*w1.y;
                    g[6]=bf2f(f[6])*w1.z; g[7]=bf2f(f[7])*w1.w;
                }
                const float* hb = hist + (size_t)b * RNDS * HIDDEN + d;

                float h[RNDS][8], p[RNDS];
                for (int r = 0; r < RNDS; ++r) {
                    const float4 a0 = *(const float4*)(hb + r * HIDDEN);
                    const float4 a1 = *(const float4*)(hb + r * HIDDEN + 4);
                    h[r][0]=a0.x; h[r][1]=a0.y; h[r][2]=a0.z; h[r][3]=a0.w;
                    h[r][4]=a1.x; h[r][5]=a1.y; h[r][6]=a1.z; h[r][7]=a1.w;
                    float s = 0.f;
                    for (int i = 0; i < 8; ++i) s += h[r][i] * g[i];
                    p[r] = s;
                }
                for (int r = 0; r < RNDS; ++r)
                    for (int m = 1; m < 64; m <<= 1)
                        p[r] += __shfl_xor(p[r], m, 64);

                float mx = -1e30f;
                for (int r = 0; r < RNDS; ++r) mx = fmaxf(mx, p[r] + ba);
                float sum = 0.f, a[RNDS];
                for (int r = 0; r < RNDS; ++r) { a[r] = __expf(p[r] + ba - mx); sum += a[r]; }
                const float inv = 1.0f / sum;

                float e[8] = {};
                for (int r = 0; r < RNDS; ++r)
                    for (int i = 0; i < 8; ++i) e[i] += a[r] * h[r][i];

                ushort4 o0, o1;
                o0.x=f2bf(e[0]*inv); o0.y=f2bf(e[1]*inv);
                o0.z=f2bf(e[2]*inv); o0.w=f2bf(e[3]*inv);
                o1.x=f2bf(e[4]*inv); o1.y=f2bf(e[5]*inv);
                o1.z=f2bf(e[6]*inv); o1.w=f2bf(e[7]*inv);
                unsigned short* q = hembb + (size_t)b * HIDDEN + d;
                *(ushort4*)q = o0;
                *(ushort4*)(q + 4) = o1;
            }
        }
    }
    GRID_BARRIER(bar + 128)

    // ---- phase 3: out = fused + tanh(hembb @ W_hist^T + b_hist) ----
    {
        const unsigned short* g_A0 = hembb; const int g_lda0 = HIDDEN;
        const unsigned short* g_A1 = hembb; const int g_lda1 = HIDDEN;
        const int g_ks = HIDDEN;           // k0 < 512 always -> A0 branch
        const int g_K  = HIDDEN;
        const unsigned short* g_Wb = Whb + (size_t)bn * g_K;
        f32x4 acc00 = {}, acc01 = {}, acc10 = {}, acc11 = {};
        GEMM_KLOOP(8)
        EPI_RESID(acc00, 0, 0, b_hist, fusedb, out)
        EPI_RESID(acc01, 0, 1, b_hist, fusedb, out)
        EPI_RESID(acc10, 1, 0, b_hist, fusedb, out)
        EPI_RESID(acc11, 1, 1, b_hist, fusedb, out)
    }
}

extern "C" void kernel_launch(void* const* d_in, const int* in_sizes, int n_in,
                              void* d_out, int out_size, void* d_ws, size_t ws_size,
                              hipStream_t stream)
{
    const float* img    = (const float*)d_in[0];
    const float* ques   = (const float*)d_in[1];
    const float* hist   = (const float*)d_in[2];
    const float* W_fuse = (const float*)d_in[3];
    const float* b_fuse = (const float*)d_in[4];
    const float* w_att  = (const float*)d_in[5];
    const float* b_att  = (const float*)d_in[6];
    const float* W_hist = (const float*)d_in[7];
    const float* b_hist = (const float*)d_in[8];

    long n_img  = in_sizes[0];
    long n_ques = in_sizes[1];
    long n_Wf   = in_sizes[3];
    long n_Wh   = in_sizes[7];
    int  BR     = (int)(n_ques / HIDDEN);   // 5120

    unsigned short* imgb   = (unsigned short*)d_ws;
    unsigned short* quesb  = imgb   + n_img;
    unsigned short* Wfb    = quesb  + n_ques;
    unsigned short* Whb    = Wfb    + n_Wf;
    unsigned short* fusedb = Whb    + n_Wh;        // BR*512 bf16
    unsigned short* hembb  = fusedb + (size_t)BR * HIDDEN;
    size_t bar_off = (size_t)((char*)(hembb + (size_t)BR * HIDDEN) - (char*)d_ws);
    bar_off = (bar_off + 255) & ~(size_t)255;
    unsigned* bar = (unsigned*)((char*)d_ws + bar_off);
    float* outp = (float*)d_out;

    // zero the 3 barrier counters (word offsets 0 / 64 / 128 -> 256B apart,
    // so spin traffic on one counter's line never aliases another's)
    hipMemsetAsync(bar, 0, 192 * sizeof(unsigned), stream);

    mega<<<dim3(NBLK), dim3(256), 0, stream>>>(
        img, ques, hist, b_fuse, w_att, b_att, b_hist, W_fuse, W_hist,
        imgb, quesb, Wfb, Whb, fusedb, hembb, outp, bar,
        n_img, n_ques, n_Wf, n_Wh, BR);
}

// Round 8
// 262.096 us; speedup vs baseline: 1.8828x; 1.5723x over previous
//
#include <hip/hip_runtime.h>
#include <hip/hip_bf16.h>

#define HIDDEN 512
#define IMGF   2048
#define RNDS   10

typedef float  f32x4  __attribute__((ext_vector_type(4)));
typedef __bf16 bf16x8 __attribute__((ext_vector_type(8)));
typedef unsigned short u16x8 __attribute__((ext_vector_type(8)));

__device__ __forceinline__ unsigned short f2bf(float x) {
    union { float f; unsigned u; } v; v.f = x;
    unsigned r = v.u + 0x7FFFu + ((v.u >> 16) & 1u);   // RNE
    return (unsigned short)(r >> 16);
}
__device__ __forceinline__ float bf2f(unsigned short h) {
    union { unsigned u; float f; } v; v.u = ((unsigned)h) << 16;
    return v.f;
}

__device__ __forceinline__ void cp16_async(const void* g, void* l) {
    __builtin_amdgcn_global_load_lds(
        (const __attribute__((address_space(1))) unsigned int*)g,
        (__attribute__((address_space(3))) unsigned int*)l,
        16, 0, 0);
}

// ---------------------------------------------------------------------------
// fp32 -> bf16 pre-convert of img / ques / W_fuse / W_hist (one BW pass).
// Grid-stride, capped at 2048 blocks (G11) instead of ~30K single-shot.
// ---------------------------------------------------------------------------
__global__ __launch_bounds__(256)
void cvt_bf16(const float* __restrict__ p0, long n0,
              const float* __restrict__ p1, long n1,
              const float* __restrict__ p2, long n2,
              const float* __restrict__ p3, long n3,
              unsigned short* __restrict__ q0, unsigned short* __restrict__ q1,
              unsigned short* __restrict__ q2, unsigned short* __restrict__ q3)
{
    const long total  = n0 + n1 + n2 + n3;
    const long stride = (long)gridDim.x * 256 * 4;
    for (long i = ((long)blockIdx.x * 256 + threadIdx.x) * 4; i < total; i += stride) {
        const float* s; unsigned short* d; long j;
        if      (i < n0)            { s = p0; d = q0; j = i; }
        else if (i < n0 + n1)       { s = p1; d = q1; j = i - n0; }
        else if (i < n0 + n1 + n2)  { s = p2; d = q2; j = i - n0 - n1; }
        else                        { s = p3; d = q3; j = i - n0 - n1 - n2; }
        float4 v = *(const float4*)(s + j);
        ushort4 o;
        o.x = f2bf(v.x); o.y = f2bf(v.y); o.z = f2bf(v.z); o.w = f2bf(v.w);
        *(ushort4*)(d + j) = o;
    }
}

// ---------------------------------------------------------------------------
// 32x64x64 bf16 MFMA GEMM, async global_load_lds staging, double-buffered.
// Small tile -> 1280 blocks (~5/CU resident, ~20 waves/CU) so K-step load
// latency is hidden by TLP instead of (compiler-defeated) pipelining.
// out[m][n] = tanh(sum_k A[m][k]*W[n][k] + bias[n]) (+ resid[m][n])
// RESID=false: write bf16 to outb.  RESID=true: out fp32 += bf16 resid.
// LDS chunk-col XOR-swizzled by (row&7): conflict-free ds_read_b128 while
// keeping the lane-contiguous LDS destinations global_load_lds requires.
// (Reverted to the round-0 geometry: best verified 256.4 us. The 64x64
// variant measured 260.7; the mega-kernel route measured 263-337 us of
// device time alone across 3 barrier variants -- falsified.)
// ---------------------------------------------------------------------------
template<bool RESID>
__global__ __launch_bounds__(256, 4)
void gemm_bt_tanh(const unsigned short* __restrict__ A0, int lda0,
                  const unsigned short* __restrict__ A1, int lda1, int kSplit,
                  const unsigned short* __restrict__ W,
                  const float* __restrict__ bias,
                  const unsigned short* __restrict__ residb,
                  float* __restrict__ outf, unsigned short* __restrict__ outb,
                  int K)
{
    __shared__ unsigned short lA[2][32 * 64];
    __shared__ unsigned short lB[2][64 * 64];

    const int bm = blockIdx.x * 32;
    const int bn = blockIdx.y * 64;
    const int t    = threadIdx.x;
    const int lane = t & 63;
    const int wave = t >> 6;
    const int wm = (wave >> 1) * 16;   // 0 / 16
    const int wn = (wave & 1) * 32;    // 0 / 32
    const int lr = lane & 15;
    const int lq = lane >> 4;

    const unsigned short* Wb0 = W + (size_t)bn * K;

    auto stage_tiles = [&](int kt, int buf) {
        int k0 = kt << 6;
        const unsigned short* Ab; int lda;
        if (k0 < kSplit) { Ab = A0 + (size_t)bm * lda0 + k0;            lda = lda0; }
        else             { Ab = A1 + (size_t)bm * lda1 + (k0 - kSplit); lda = lda1; }
        {   // A: 32x64 = 256 chunks of 16B, one per thread
            int r = t >> 3, s = (t & 7) ^ (r & 7);
            cp16_async(Ab + (size_t)r * lda + s * 8, &lA[buf][t * 8]);
        }
        #pragma unroll
        for (int h = 0; h < 2; ++h) {   // B: 64x64 = 512 chunks
            int ci = h * 256 + t;
            int r = ci >> 3, s = (ci & 7) ^ (r & 7);
            cp16_async(Wb0 + k0 + (size_t)r * K + s * 8, &lB[buf][ci * 8]);
        }
    };

    f32x4 acc[2] = {};
    const int NT = K >> 6;

    stage_tiles(0, 0);
    for (int kt = 0; kt < NT; ++kt) {
        __syncthreads();                                   // drains tile-kt loads
        if (kt + 1 < NT) stage_tiles(kt + 1, (kt + 1) & 1); // async prefetch
        const unsigned short* a = &lA[kt & 1][0];
        const unsigned short* b = &lB[kt & 1][0];
        #pragma unroll
        for (int kh = 0; kh < 2; ++kh) {
            const int c = kh * 4 + lq;
            const int ra = wm + lr;
            bf16x8 af = __builtin_bit_cast(bf16x8,
                *(const u16x8*)&a[ra * 64 + ((c ^ (ra & 7)) * 8)]);
            #pragma unroll
            for (int ni = 0; ni < 2; ++ni) {
                const int rb = wn + ni * 16 + lr;
                bf16x8 bf = __builtin_bit_cast(bf16x8,
                    *(const u16x8*)&b[rb * 64 + ((c ^ (rb & 7)) * 8)]);
                acc[ni] = __builtin_amdgcn_mfma_f32_16x16x32_bf16(
                    af, bf, acc[ni], 0, 0, 0);
            }
        }
    }

    // epilogue: D[m = lq*4 + j][n = lr]  (verified m89/m91 layout)
    #pragma unroll
    for (int ni = 0; ni < 2; ++ni) {
        const int col = bn + wn + ni * 16 + lr;
        const float bc = bias[col];
        const int rbase = bm + wm + lq * 4;
        #pragma unroll
        for (int j = 0; j < 4; ++j) {
            const size_t idx = (size_t)(rbase + j) * HIDDEN + col;
            float v = tanhf(acc[ni][j] + bc);
            if (RESID) outf[idx] = v + bf2f(residb[idx]);
            else       outb[idx] = f2bf(v);
        }
    }
}

// ---------------------------------------------------------------------------
// Attention: one wave per BR-row, lane holds 8 dims x 10 rounds in registers.
// No LDS, no barriers. fused is bf16; writes hist_embed as bf16 (GEMM2's A).
// ---------------------------------------------------------------------------
__global__ __launch_bounds__(256)
void attn_embed(const float* __restrict__ hist,
                const unsigned short* __restrict__ fusedb,
                const float* __restrict__ w_att,
                const float* __restrict__ b_att,
                unsigned short* __restrict__ hembed)
{
    const int lane = threadIdx.x & 63;
    const int wave = threadIdx.x >> 6;
    const int b = blockIdx.x * 4 + wave;
    const int d = lane * 8;

    float g[8];
    {
        u16x8 f = *(const u16x8*)(fusedb + (size_t)b * HIDDEN + d);
        const float4 w0 = *(const float4*)(w_att + d);
        const float4 w1 = *(const float4*)(w_att + d + 4);
        g[0]=bf2f(f[0])*w0.x; g[1]=bf2f(f[1])*w0.y; g[2]=bf2f(f[2])*w0.z; g[3]=bf2f(f[3])*w0.w;
        g[4]=bf2f(f[4])*w1.x; g[5]=bf2f(f[5])*w1.y; g[6]=bf2f(f[6])*w1.z; g[7]=bf2f(f[7])*w1.w;
    }
    const float* hb = hist + (size_t)b * RNDS * HIDDEN + d;

    float h[RNDS][8], p[RNDS];
    #pragma unroll
    for (int r = 0; r < RNDS; ++r) {
        const float4 a0 = *(const float4*)(hb + r * HIDDEN);
        const float4 a1 = *(const float4*)(hb + r * HIDDEN + 4);
        h[r][0]=a0.x; h[r][1]=a0.y; h[r][2]=a0.z; h[r][3]=a0.w;
        h[r][4]=a1.x; h[r][5]=a1.y; h[r][6]=a1.z; h[r][7]=a1.w;
        float s = 0.f;
        #pragma unroll
        for (int i = 0; i < 8; ++i) s += h[r][i] * g[i];
        p[r] = s;
    }
    #pragma unroll
    for (int r = 0; r < RNDS; ++r)
        #pragma unroll
        for (int m = 1; m < 64; m <<= 1)
            p[r] += __shfl_xor(p[r], m, 64);

    const float ba = b_att[0];
    float mx = -1e30f;
    #pragma unroll
    for (int r = 0; r < RNDS; ++r) mx = fmaxf(mx, p[r] + ba);
    float sum = 0.f, a[RNDS];
    #pragma unroll
    for (int r = 0; r < RNDS; ++r) { a[r] = __expf(p[r] + ba - mx); sum += a[r]; }
    const float inv = 1.0f / sum;

    float e[8] = {};
    #pragma unroll
    for (int r = 0; r < RNDS; ++r)
        #pragma unroll
        for (int i = 0; i < 8; ++i) e[i] += a[r] * h[r][i];

    ushort4 o0, o1;
    o0.x=f2bf(e[0]*inv); o0.y=f2bf(e[1]*inv); o0.z=f2bf(e[2]*inv); o0.w=f2bf(e[3]*inv);
    o1.x=f2bf(e[4]*inv); o1.y=f2bf(e[5]*inv); o1.z=f2bf(e[6]*inv); o1.w=f2bf(e[7]*inv);
    unsigned short* q = hembed + (size_t)b * HIDDEN + d;
    *(ushort4*)q = o0;
    *(ushort4*)(q + 4) = o1;
}

extern "C" void kernel_launch(void* const* d_in, const int* in_sizes, int n_in,
                              void* d_out, int out_size, void* d_ws, size_t ws_size,
                              hipStream_t stream)
{
    const float* img    = (const float*)d_in[0];
    const float* ques   = (const float*)d_in[1];
    const float* hist   = (const float*)d_in[2];
    const float* W_fuse = (const float*)d_in[3];
    const float* b_fuse = (const float*)d_in[4];
    const float* w_att  = (const float*)d_in[5];
    const float* b_att  = (const float*)d_in[6];
    const float* W_hist = (const float*)d_in[7];
    const float* b_hist = (const float*)d_in[8];

    const long n_img  = in_sizes[0];
    const long n_ques = in_sizes[1];
    const long n_Wf   = in_sizes[3];
    const long n_Wh   = in_sizes[7];
    const int  BR     = (int)(n_ques / HIDDEN);   // 5120

    unsigned short* imgb   = (unsigned short*)d_ws;
    unsigned short* quesb  = imgb   + n_img;
    unsigned short* Wfb    = quesb  + n_ques;
    unsigned short* Whb    = Wfb    + n_Wf;
    unsigned short* fusedb = Whb    + n_Wh;        // BR*512 bf16
    unsigned short* hembb  = fusedb + (size_t)BR * HIDDEN;

    // 1) fp32 -> bf16 conversions (img, ques, W_fuse, W_hist), capped grid
    const long total4 = (n_img + n_ques + n_Wf + n_Wh) / 4;
    unsigned cvtBlocks = (unsigned)((total4 + 255) / 256);
    if (cvtBlocks > 2048u) cvtBlocks = 2048u;
    cvt_bf16<<<dim3(cvtBlocks), dim3(256), 0, stream>>>(
        img, n_img, ques, n_ques, W_fuse, n_Wf, W_hist, n_Wh,
        imgb, quesb, Wfb, Whb);

    dim3 blk(256);
    dim3 g1(BR / 32, HIDDEN / 64);   // 160 x 8 = 1280 blocks

    // 2) fusedb = tanh(cat(img,ques) @ W_fuse^T + b_fuse)   (bf16)
    gemm_bt_tanh<false><<<g1, blk, 0, stream>>>(
        imgb, IMGF, quesb, HIDDEN, IMGF,
        Wfb, b_fuse, nullptr, nullptr, fusedb, IMGF + HIDDEN);

    // 3) attention + weighted history sum -> hembb (bf16)
    attn_embed<<<dim3(BR / 4), blk, 0, stream>>>(hist, fusedb, w_att, b_att, hembb);

    // 4) out = fused + tanh(hembb @ W_hist^T + b_hist)
    gemm_bt_tanh<true><<<g1, blk, 0, stream>>>(
        hembb, HIDDEN, nullptr, 0, HIDDEN,
        Whb, b_hist, fusedb, (float*)d_out, nullptr, HIDDEN);
}